// Round 8
// baseline (441.451 us; speedup 1.0000x reference)
//
#include <hip/hip_runtime.h>
#include <hip/hip_bf16.h>
#include <hip/hip_fp16.h>
#include <math.h>

// QAT GPT2 MLP + LoRA on MI355X — fp32 in/out.
// Round 8: hedged rewrite after two container-level failures of round 6/7.
// Keeps the intended fix for the 99us quant_h_t2 hotspot (persistent blocks,
// A_proj slice in registers -> A traffic 1 GiB -> 64 MB) but drops every
// round-6-new construct that could have upset the toolchain: no shfl_xor
// fold, no float atomicAdd accumulation, no __launch_bounds__(256,2), no
// 512KB memset. Reductions use the round-3..5-proven shfl_down + LDS tree;
// t1/t2 written directly (one block owns each row). quant_x_t1 reverted to
// the round-5 version verbatim. GEMMs (i8 MFMA, XOR-swizzle, 0 conflicts),
// absmax, quant_w byte-identical to the passing round 5.

typedef unsigned short u16;
typedef unsigned int u32;
typedef signed char i8;
typedef int i32x4 __attribute__((ext_vector_type(4)));

#define ASYNC16(gp, lp)                                                        \
  __builtin_amdgcn_global_load_lds(                                            \
      (__attribute__((address_space(1))) void*)(gp),                           \
      (__attribute__((address_space(3))) void*)(lp), 16, 0, 0)

__device__ __forceinline__ int quanti(float v, float inv) {
  float q = rintf(v * inv);
  q = fminf(fmaxf(q, -128.0f), 127.0f);
  return (int)q;
}

__device__ __forceinline__ float load_scale(const u32* slot) {
  return fmaxf(__uint_as_float(*slot) * (1.0f / 127.0f), 1e-8f);
}

// exact-erf GELU via Abramowitz-Stegun 7.1.26 (|erf err| <= 1.5e-7)
__device__ __forceinline__ float gelu_erf(float v) {
  float z = fabsf(v) * 0.70710678118654752f;
  float t = __builtin_amdgcn_rcpf(fmaf(0.3275911f, z, 1.0f));
  float poly =
      t * fmaf(t,
               fmaf(t,
                    fmaf(t, fmaf(t, 1.061405429f, -1.453152027f),
                         1.421413741f),
                    -0.284496736f),
               0.254829592f);
  float e = fmaf(-poly, exp2f(-z * z * 1.4426950408889634f), 1.0f);
  return 0.5f * v * fmaf(copysignf(e, v), 1.0f, 1.0f);
}

// -------------------- absmax over fp32 tensor (float4 grid-stride) ----------
__global__ void absmax_kernel(const float* __restrict__ x, int n4,
                              u32* __restrict__ slot) {
  float m = 0.0f;
  int stride = gridDim.x * blockDim.x;
  for (int i = blockIdx.x * blockDim.x + threadIdx.x; i < n4; i += stride) {
    float4 v = ((const float4*)x)[i];
    m = fmaxf(m, fmaxf(fmaxf(fabsf(v.x), fabsf(v.y)),
                       fmaxf(fabsf(v.z), fabsf(v.w))));
  }
#pragma unroll
  for (int off = 32; off > 0; off >>= 1) m = fmaxf(m, __shfl_down(m, off));
  __shared__ float wmax[4];
  int lane = threadIdx.x & 63, wave = threadIdx.x >> 6;
  if (lane == 0) wmax[wave] = m;
  __syncthreads();
  if (threadIdx.x == 0) {
    m = fmaxf(fmaxf(wmax[0], wmax[1]), fmaxf(wmax[2], wmax[3]));
    atomicMax(slot, __float_as_uint(m));  // positive floats: bit-monotone
  }
}

// ---------------- quantize W (fp32 in, packed i8 out) -----------------------
__global__ void quant_w_kernel(const float* __restrict__ w, int n16,
                               const u32* __restrict__ slot,
                               i8* __restrict__ q) {
  float inv = 1.0f / load_scale(slot);
  int stride = gridDim.x * blockDim.x;
  for (int i = blockIdx.x * blockDim.x + threadIdx.x; i < n16; i += stride) {
    const float4* src = (const float4*)w + i * 4;
    u32 pk[4];
#pragma unroll
    for (int c = 0; c < 4; c++) {
      float4 v = src[c];
      pk[c] = ((u32)(quanti(v.x, inv) & 255)) |
              ((u32)(quanti(v.y, inv) & 255) << 8) |
              ((u32)(quanti(v.z, inv) & 255) << 16) |
              ((u32)(quanti(v.w, inv) & 255) << 24);
    }
    uint4 o = {pk[0], pk[1], pk[2], pk[3]};
    ((uint4*)q)[i] = o;
  }
}

// ---- quantize x + t1[m][r] = sum_i x[m,i]*Afc[r,i]  (block per row) --------
// (round-5 version verbatim — was not a top-5 dispatch)
__global__ void quant_x_t1_kernel(const float* __restrict__ x,
                                  const float* __restrict__ A,  // [8][1024]
                                  const u32* __restrict__ slot,
                                  i8* __restrict__ q,
                                  float* __restrict__ t1) {
  int row = blockIdx.x, tid = threadIdx.x;
  float inv = 1.0f / load_scale(slot);
  float4 v = ((const float4*)(x + (long)row * 1024))[tid];
  u32 pk = ((u32)(quanti(v.x, inv) & 255)) |
           ((u32)(quanti(v.y, inv) & 255) << 8) |
           ((u32)(quanti(v.z, inv) & 255) << 16) |
           ((u32)(quanti(v.w, inv) & 255) << 24);
  ((u32*)(q + (long)row * 1024))[tid] = pk;
  float p[8];
#pragma unroll
  for (int r = 0; r < 8; r++) {
    float4 a = ((const float4*)(A + r * 1024))[tid];
    p[r] = v.x * a.x + v.y * a.y + v.z * a.z + v.w * a.w;
  }
#pragma unroll
  for (int r = 0; r < 8; r++)
#pragma unroll
    for (int off = 32; off > 0; off >>= 1) p[r] += __shfl_down(p[r], off);
  __shared__ float red[4][8];
  int lane = tid & 63, wave = tid >> 6;
  if (lane == 0) {
#pragma unroll
    for (int r = 0; r < 8; r++) red[wave][r] = p[r];
  }
  __syncthreads();
  if (tid < 8)
    t1[(long)row * 8 + tid] =
        red[0][tid] + red[1][tid] + red[2][tid] + red[3][tid];
}

// ---- quantize h (fp16 -> i8 in place) + t2 = h@Aproj^T ---------------------
// Persistent: 16 rows/block, thread owns cols [tid*16, tid*16+16), the
// A[8][16] slice lives in registers (read ONCE per block, not per row).
// Reduction: proven shfl_down + LDS tree; t2 written directly (no atomics).
__global__ void quant_h_t2_kernel(
    u16* __restrict__ h,          // [8192][4096] fp16; i8 row in first half
    const float* __restrict__ A,  // [8][4096]
    const u32* __restrict__ slot,
    float* __restrict__ t2) {
  int tid = threadIdx.x, lane = tid & 63, wave = tid >> 6;
  float inv = 1.0f / load_scale(slot);
  float4 a[8][4];
#pragma unroll
  for (int r = 0; r < 8; r++)
#pragma unroll
    for (int c = 0; c < 4; c++)
      a[r][c] = ((const float4*)(A + r * 4096 + tid * 16))[c];
  __shared__ float red[4][8];
  int r0 = blockIdx.x * 16;
  for (int rr = 0; rr < 16; rr++) {
    long row = r0 + rr;
    u16* hp = h + row * 4096 + tid * 16;
    uint4 u0 = ((const uint4*)hp)[0];
    uint4 u1 = ((const uint4*)hp)[1];
    u32 uu[8] = {u0.x, u0.y, u0.z, u0.w, u1.x, u1.y, u1.z, u1.w};
    float hv[16];
#pragma unroll
    for (int e = 0; e < 8; e++) {
      __half2 hh = *(__half2*)&uu[e];
      float2 f = __half22float2(hh);
      hv[2 * e] = f.x;
      hv[2 * e + 1] = f.y;
    }
    float p[8];
#pragma unroll
    for (int r = 0; r < 8; r++) {
      float s = 0.0f;
#pragma unroll
      for (int c = 0; c < 4; c++)
        s += a[r][c].x * hv[4 * c + 0] + a[r][c].y * hv[4 * c + 1] +
             a[r][c].z * hv[4 * c + 2] + a[r][c].w * hv[4 * c + 3];
      p[r] = s;
    }
    // barrier 1: all reads of this fp16 row complete before the in-place i8
    // overwrite; also separates last iter's red[] read from this iter's write
    __syncthreads();
    u32 pk[4];
#pragma unroll
    for (int c = 0; c < 4; c++)
      pk[c] = ((u32)(quanti(hv[4 * c + 0], inv) & 255)) |
              ((u32)(quanti(hv[4 * c + 1], inv) & 255) << 8) |
              ((u32)(quanti(hv[4 * c + 2], inv) & 255) << 16) |
              ((u32)(quanti(hv[4 * c + 3], inv) & 255) << 24);
    uint4 o = {pk[0], pk[1], pk[2], pk[3]};
    *(uint4*)((i8*)h + row * 8192 + tid * 16) = o;
#pragma unroll
    for (int r = 0; r < 8; r++)
#pragma unroll
      for (int off = 32; off > 0; off >>= 1) p[r] += __shfl_down(p[r], off);
    if (lane == 0) {
#pragma unroll
      for (int r = 0; r < 8; r++) red[wave][r] = p[r];
    }
    __syncthreads();  // barrier 2: red[] ready
    if (tid < 8)
      t2[row * 8 + tid] =
          red[0][tid] + red[1][tid] + red[2][tid] + red[3][tid];
  }
}

// ------------- main GEMM: C = Aq * Bq^T (i8), 128x128 tile, BK=128 ---------
// A: [M] rows stride lda bytes, B: [N] rows stride ldb bytes, K-major i8.
// LDS XOR-swizzle: phys 16B-chunk p at row r holds logical chunk p^(r&7).
// MODE 0: *scale + bias + 2*t.Bl, GELU(erf), store FP16 h, absmax(h).
// MODE 1: *scale + bias + 2*t.Bl, store fp32 to d_out.
template <int MODE>
__launch_bounds__(256) __global__
    void gemm_kernel(const i8* __restrict__ A, const i8* __restrict__ B,
                     int N, int K, int lda, int ldb,
                     const float* __restrict__ bias,
                     const float* __restrict__ tl,   // [M][8] f32
                     const float* __restrict__ Bl,   // [N][8] f32
                     const u32* __restrict__ scales, int sa, int sb,
                     void* __restrict__ outp, u32* __restrict__ hmax) {
  __shared__ i8 As[128 * 128];
  __shared__ i8 Bs[128 * 128];
  __shared__ u32 bmax;
  int tid = threadIdx.x;
  int lane = tid & 63, wave = tid >> 6;
  int quad = lane >> 4, l15 = lane & 15;
  int wm = (wave & 1) * 64, wn = (wave >> 1) * 64;
  long m0 = (long)blockIdx.y * 128;
  long n0 = (long)blockIdx.x * 128;
  if (MODE == 0 && tid == 0) bmax = 0u;

  const i8* gA[4];
  const i8* gB[4];
  int ldsOff[4];
#pragma unroll
  for (int i = 0; i < 4; i++) {
    int c = i * 256 + tid;
    int row = c >> 3;
    int kc = ((c & 7) ^ (row & 7)) * 16;  // swizzled source k-offset (bytes)
    gA[i] = A + (m0 + row) * lda + kc;
    gB[i] = B + (n0 + row) * ldb + kc;
    ldsOff[i] = c * 16;
  }
  int s0 = (quad ^ (l15 & 7)) * 16;
  int s1 = s0 ^ 64;

  i32x4 acc[4][4] = {};
  int nit = K >> 7;
  for (int k = 0; k < nit; k++) {
#pragma unroll
    for (int i = 0; i < 4; i++) {
      ASYNC16(gA[i], As + ldsOff[i]);
      ASYNC16(gB[i], Bs + ldsOff[i]);
      gA[i] += 128;
      gB[i] += 128;
    }
    __syncthreads();
#pragma unroll
    for (int kk = 0; kk < 2; kk++) {
      int ko = kk ? s1 : s0;
      i32x4 af[4], bfr[4];
#pragma unroll
      for (int i = 0; i < 4; i++)
        af[i] = *(const i32x4*)(As + (wm + i * 16 + l15) * 128 + ko);
#pragma unroll
      for (int j = 0; j < 4; j++)
        bfr[j] = *(const i32x4*)(Bs + (wn + j * 16 + l15) * 128 + ko);
#pragma unroll
      for (int i = 0; i < 4; i++)
#pragma unroll
        for (int j = 0; j < 4; j++)
          acc[i][j] = __builtin_amdgcn_mfma_i32_16x16x64_i8(
              af[i], bfr[j], acc[i][j], 0, 0, 0);
    }
    __syncthreads();
  }

  // epilogue
  float scale = load_scale(scales + sa) * load_scale(scales + sb);
  float biasv[4];
  float4 bl0[4], bl1[4];
#pragma unroll
  for (int j = 0; j < 4; j++) {
    long n = n0 + wn + j * 16 + l15;
    biasv[j] = bias[n];
    bl0[j] = ((const float4*)(Bl + n * 8))[0];
    bl1[j] = ((const float4*)(Bl + n * 8))[1];
  }
  float lmax = 0.0f;
#pragma unroll
  for (int i = 0; i < 4; i++) {
#pragma unroll
    for (int r = 0; r < 4; r++) {
      long m = m0 + wm + i * 16 + quad * 4 + r;
      float4 t0 = ((const float4*)(tl + m * 8))[0];
      float4 t1v = ((const float4*)(tl + m * 8))[1];
#pragma unroll
      for (int j = 0; j < 4; j++) {
        long n = n0 + wn + j * 16 + l15;
        float lora = t0.x * bl0[j].x + t0.y * bl0[j].y + t0.z * bl0[j].z +
                     t0.w * bl0[j].w + t1v.x * bl1[j].x + t1v.y * bl1[j].y +
                     t1v.z * bl1[j].z + t1v.w * bl1[j].w;
        float v = (float)acc[i][j][r] * scale + biasv[j] + 2.0f * lora;
        if (MODE == 0) {
          float hv = gelu_erf(v);
          __half hh = __float2half_rn(hv);
          ((u16*)outp)[m * N + n] = *(u16*)&hh;
          lmax = fmaxf(lmax, fabsf(hv));
        } else {
          ((float*)outp)[m * N + n] = v;
        }
      }
    }
  }
  if (MODE == 0) {
    atomicMax(&bmax, __float_as_uint(lmax));
    __syncthreads();
    if (tid == 0) atomicMax(hmax, bmax);
  }
}

extern "C" void kernel_launch(void* const* d_in, const int* in_sizes, int n_in,
                              void* d_out, int out_size, void* d_ws,
                              size_t ws_size, hipStream_t stream) {
  const float* x = (const float*)d_in[0];    // [8192][1024]
  const float* Wfc = (const float*)d_in[1];  // [4096][1024]
  const float* bfc = (const float*)d_in[2];  // [4096]
  const float* Afc = (const float*)d_in[3];  // [8][1024]
  const float* Bfc = (const float*)d_in[4];  // [4096][8]
  const float* Wpr = (const float*)d_in[5];  // [1024][4096]
  const float* bpr = (const float*)d_in[6];  // [1024]
  const float* Apr = (const float*)d_in[7];  // [8][4096]
  const float* Bpr = (const float*)d_in[8];  // [1024][8]
  float* out = (float*)d_out;                // fp32 [8192][1024]

  char* w = (char*)d_ws;
  u32* scales = (u32*)w;                   // 4 slots (fp32 bits): x, Wfc, Wpr, h
  float* t1 = (float*)(w + 256);           // [8192][8]
  float* t2 = (float*)(w + 256 + 262144);  // [8192][8]
  i8* xq = (i8*)(w + 524544);              // [8192][1024] i8
  i8* wq1 = (i8*)(w + 9437184);            // [4096][1024] i8
  i8* wq2 = (i8*)(w + 13631488);           // [1024][4096] i8
  u16* hq = (u16*)(w + 17825792);          // [8192][4096] fp16 h; i8 in place
  if (ws_size < 84934656) return;          // need ~81 MiB scratch

  hipMemsetAsync(scales, 0, 256, stream);
  absmax_kernel<<<1024, 256, 0, stream>>>(x, 8192 * 1024 / 4, scales + 0);
  absmax_kernel<<<512, 256, 0, stream>>>(Wfc, 4096 * 1024 / 4, scales + 1);
  absmax_kernel<<<512, 256, 0, stream>>>(Wpr, 4096 * 1024 / 4, scales + 2);
  quant_x_t1_kernel<<<8192, 256, 0, stream>>>(x, Afc, scales + 0, xq, t1);
  quant_w_kernel<<<256, 256, 0, stream>>>(Wfc, 4096 * 1024 / 16, scales + 1,
                                          wq1);
  quant_w_kernel<<<256, 256, 0, stream>>>(Wpr, 4096 * 1024 / 16, scales + 2,
                                          wq2);
  gemm_kernel<0><<<dim3(32, 64), 256, 0, stream>>>(
      xq, wq1, 4096, 1024, 1024, 1024, bfc, t1, Bfc, scales, 0, 1, hq,
      scales + 3);
  quant_h_t2_kernel<<<512, 256, 0, stream>>>(hq, Apr, scales + 3, t2);
  gemm_kernel<1><<<dim3(8, 64), 256, 0, stream>>>(
      (const i8*)hq, wq2, 1024, 4096, 8192, 4096, bpr, t2, Bpr, scales, 3, 2,
      out, nullptr);
}